// Round 1
// baseline (1112.471 us; speedup 1.0000x reference)
//
#include <hip/hip_runtime.h>

#define NODE_F 128
#define ENT_F  256
#define LDO    768   // out row stride: ENT_F * (DEPTH+1)

// ---------- helpers ----------
__device__ __forceinline__ unsigned f2mono(float x) {
    unsigned u = __float_as_uint(x);
    return (u & 0x80000000u) ? ~u : (u | 0x80000000u);
}
__device__ __forceinline__ float mono2f(unsigned u) {
    return (u & 0x80000000u) ? __uint_as_float(u & 0x7FFFFFFFu)
                             : __uint_as_float(~u);
}

// ---------- kernels ----------
__global__ void count_deg_k(const int* __restrict__ row, int* __restrict__ deg, int E) {
    int i = blockIdx.x * blockDim.x + threadIdx.x;
    if (i < E) atomicAdd(&deg[row[i]], 1);
}

// out[row[e]*LDO + off + f] += emb[col[e]*128 + f] / deg[row[e]]   (f in [0,128))
__global__ void mean_agg_k(const int* __restrict__ row, const int* __restrict__ col,
                           const float* __restrict__ emb, const int* __restrict__ deg,
                           float* __restrict__ out, int off, int E) {
    int e = blockIdx.x;
    int f = threadIdx.x;               // blockDim.x == 128
    if (e >= E) return;
    int r = row[e], c = col[e];
    float w = 1.0f / (float)deg[r];
    atomicAdd(&out[(size_t)r * LDO + off + f], emb[(size_t)c * NODE_F + f] * w);
}

__global__ void relu_cols_k(float* __restrict__ out, int off, size_t total) {
    size_t i = (size_t)blockIdx.x * blockDim.x + threadIdx.x;
    if (i >= total) return;
    size_t n = i >> 8;                 // /256
    int    c = (int)(i & 255);
    float* p = &out[n * LDO + off + c];
    float v = *p;
    *p = v > 0.0f ? v : 0.0f;
}

__global__ void rel_proj_k(const float* __restrict__ rel_emb, const float* __restrict__ a_rel,
                           float* __restrict__ proj, int R) {
    int r = blockIdx.x * blockDim.x + threadIdx.x;
    if (r >= R) return;
    float s = 0.0f;
    #pragma unroll 4
    for (int f = 0; f < NODE_F; ++f) s += rel_emb[(size_t)r * NODE_F + f] * a_rel[f];
    proj[r] = s;
}

__global__ void rel_attn_k(const float* __restrict__ sp_val, const int* __restrict__ sp_row,
                           const int* __restrict__ sp_col, const float* __restrict__ proj,
                           float* __restrict__ rel_attn, int E) {
    int e = blockIdx.x * blockDim.x + threadIdx.x;
    if (e < E) atomicAdd(&rel_attn[sp_row[e]], sp_val[e] * proj[sp_col[e]]);
}

// one 64-lane wave per node: a_s[n] = feat(n)·a_self, a_n[n] = feat(n)·a_neigh
__global__ void asn_k(const float* __restrict__ out, int off,
                      const float* __restrict__ a_self, const float* __restrict__ a_neigh,
                      float* __restrict__ a_s, float* __restrict__ a_n, int N) {
    int wavesPerBlock = blockDim.x >> 6;
    int n = blockIdx.x * wavesPerBlock + (threadIdx.x >> 6);
    int lane = threadIdx.x & 63;
    if (n >= N) return;
    const float4* fp = reinterpret_cast<const float4*>(&out[(size_t)n * LDO + off]);
    float4 v  = fp[lane];
    float4 s4 = reinterpret_cast<const float4*>(a_self)[lane];
    float4 n4 = reinterpret_cast<const float4*>(a_neigh)[lane];
    float ds = v.x * s4.x + v.y * s4.y + v.z * s4.z + v.w * s4.w;
    float dn = v.x * n4.x + v.y * n4.y + v.z * n4.z + v.w * n4.w;
    #pragma unroll
    for (int o = 32; o > 0; o >>= 1) {
        ds += __shfl_down(ds, o);
        dn += __shfl_down(dn, o);
    }
    if (lane == 0) { a_s[n] = ds; a_n[n] = dn; }
}

__global__ void att1_k(const float* __restrict__ rel_attn, const int* __restrict__ arow,
                       const int* __restrict__ acol, const float* __restrict__ a_s,
                       const float* __restrict__ a_n, float* __restrict__ att_raw,
                       unsigned* __restrict__ mkeys, int E) {
    int e = blockIdx.x * blockDim.x + threadIdx.x;
    if (e >= E) return;
    int r = arow[e], c = acol[e];
    float v = rel_attn[e] + a_s[r] + a_n[c];
    v = v >= 0.0f ? v : 0.2f * v;      // leaky relu
    att_raw[e] = v;
    atomicMax(&mkeys[r], f2mono(v));
}

__global__ void att2_k(const int* __restrict__ arow, const unsigned* __restrict__ mkeys,
                       float* __restrict__ att, float* __restrict__ ssum, int E) {
    int e = blockIdx.x * blockDim.x + threadIdx.x;
    if (e >= E) return;
    int r = arow[e];
    float ex = expf(att[e] - mono2f(mkeys[r]));
    att[e] = ex;
    atomicAdd(&ssum[r], ex);
}

__global__ void att3_k(const int* __restrict__ arow, const float* __restrict__ ssum,
                       float* __restrict__ att, float* __restrict__ att_out, int E) {
    int e = blockIdx.x * blockDim.x + threadIdx.x;
    if (e >= E) return;
    float a = att[e] / ssum[arow[e]];
    att[e] = a;
    att_out[e] = a;
}

// out[row[e]*LDO + dst + f] += att[e] * out[col[e]*LDO + src + f]   (f in [0,256))
__global__ void agg_k(const int* __restrict__ arow, const int* __restrict__ acol,
                      const float* __restrict__ att, float* __restrict__ out,
                      int src, int dst, int E) {
    int e = blockIdx.x;
    int f = threadIdx.x;               // blockDim.x == 256
    if (e >= E) return;
    int r = arow[e], c = acol[e];
    float a = att[e];
    atomicAdd(&out[(size_t)r * LDO + dst + f], a * out[(size_t)c * LDO + src + f]);
}

// ---------- launch ----------
extern "C" void kernel_launch(void* const* d_in, const int* in_sizes, int n_in,
                              void* d_out, int out_size, void* d_ws, size_t ws_size,
                              hipStream_t stream) {
    const float* ent_emb = (const float*)d_in[0];
    const float* rel_emb = (const float*)d_in[1];
    const float* a_self  = (const float*)d_in[2];
    const float* a_neigh = (const float*)d_in[3];
    const float* a_rel   = (const float*)d_in[4];
    const float* sp_val  = (const float*)d_in[5];
    const int*   adj_row = (const int*)d_in[6];
    const int*   adj_col = (const int*)d_in[7];
    const int*   sp_row  = (const int*)d_in[8];
    const int*   sp_col  = (const int*)d_in[9];
    const int*   rel_row = (const int*)d_in[10];
    const int*   rel_col = (const int*)d_in[11];
    const int*   ent_row = (const int*)d_in[12];
    const int*   ent_col = (const int*)d_in[13];

    const int N  = in_sizes[0] / NODE_F;
    const int R  = in_sizes[1] / NODE_F;
    const int E  = in_sizes[5];
    const int ER = in_sizes[10];
    const int EE = in_sizes[12];

    float* out = (float*)d_out;
    float* att_out = out + (size_t)N * LDO;   // final att goes here

    // workspace layout (all 16B-aligned given sizes)
    char* w = (char*)d_ws;
    float*    ws_att   = (float*)w;    w += (size_t)E * 4;   // att_raw -> exp -> normalized
    float*    rel_attn = (float*)w;    w += (size_t)E * 4;
    float*    proj     = (float*)w;    w += (size_t)R * 4;
    float*    a_s      = (float*)w;    w += (size_t)N * 4;
    float*    a_n      = (float*)w;    w += (size_t)N * 4;
    int*      deg_rel  = (int*)w;      w += (size_t)N * 4;
    int*      deg_ent  = (int*)w;      w += (size_t)N * 4;
    unsigned* mkeys    = (unsigned*)w; w += (size_t)N * 4;
    float*    ssum     = (float*)w;    w += (size_t)N * 4;

    const int TB = 256;
    const int gE = (E + TB - 1) / TB;

    // zero output (serves as accumulator init for all three column slices)
    hipMemsetAsync(d_out, 0, (size_t)out_size * sizeof(float), stream);

    // degrees
    hipMemsetAsync(deg_rel, 0, (size_t)N * 2 * sizeof(int), stream);  // deg_rel + deg_ent
    count_deg_k<<<(ER + TB - 1) / TB, TB, 0, stream>>>(rel_row, deg_rel, ER);
    count_deg_k<<<(EE + TB - 1) / TB, TB, 0, stream>>>(ent_row, deg_ent, EE);

    // mean aggregation: ent -> cols 0..127, rel -> cols 128..255
    mean_agg_k<<<EE, 128, 0, stream>>>(ent_row, ent_col, ent_emb, deg_ent, out, 0, EE);
    mean_agg_k<<<ER, 128, 0, stream>>>(rel_row, rel_col, rel_emb, deg_rel, out, NODE_F, ER);
    relu_cols_k<<<(int)(((size_t)N * ENT_F + TB - 1) / TB), TB, 0, stream>>>(out, 0, (size_t)N * ENT_F);

    // relation attention term (constant across depth)
    rel_proj_k<<<(R + TB - 1) / TB, TB, 0, stream>>>(rel_emb, a_rel, proj, R);
    hipMemsetAsync(rel_attn, 0, (size_t)E * sizeof(float), stream);
    rel_attn_k<<<gE, TB, 0, stream>>>(sp_val, sp_row, sp_col, proj, rel_attn, E);

    for (int d = 1; d <= 2; ++d) {
        const int src = (d - 1) * ENT_F;
        const int dst = d * ENT_F;

        asn_k<<<(N + 3) / 4, 256, 0, stream>>>(out, src, a_self, a_neigh, a_s, a_n, N);

        hipMemsetAsync(mkeys, 0, (size_t)N * 2 * sizeof(int), stream);  // mkeys + ssum
        att1_k<<<gE, TB, 0, stream>>>(rel_attn, adj_row, adj_col, a_s, a_n, ws_att, mkeys, E);
        att2_k<<<gE, TB, 0, stream>>>(adj_row, mkeys, ws_att, ssum, E);
        att3_k<<<gE, TB, 0, stream>>>(adj_row, ssum, ws_att, att_out, E);

        agg_k<<<E, ENT_F, 0, stream>>>(adj_row, adj_col, ws_att, out, src, dst, E);
        relu_cols_k<<<(int)(((size_t)N * ENT_F + TB - 1) / TB), TB, 0, stream>>>(out, dst, (size_t)N * ENT_F);
    }
}

// Round 2
// 424.762 us; speedup vs baseline: 2.6190x; 2.6190x over previous
//
#include <hip/hip_runtime.h>

#define NODE_F 128
#define ENT_F  256
#define LDO    768   // out row stride: ENT_F * (DEPTH+1)

// ================= CSR build =================

__global__ void count_deg_k(const int* __restrict__ row, int* __restrict__ deg, int E) {
    int i = blockIdx.x * blockDim.x + threadIdx.x;
    if (i < E) atomicAdd(&deg[row[i]], 1);
}

// per-256-chunk sums of deg
__global__ void blocksum_k(const int* __restrict__ deg, int* __restrict__ bsum, int N) {
    __shared__ int s[256];
    int i = blockIdx.x * 256 + threadIdx.x;
    s[threadIdx.x] = (i < N) ? deg[i] : 0;
    __syncthreads();
    for (int o = 128; o > 0; o >>= 1) {
        if (threadIdx.x < o) s[threadIdx.x] += s[threadIdx.x + o];
        __syncthreads();
    }
    if (threadIdx.x == 0) bsum[blockIdx.x] = s[0];
}

// exclusive scan of bsum (nb <= 512), also writes total edge count to rs_tail
__global__ void scanbsum_k(int* __restrict__ bsum, int nb, int* __restrict__ rs_tail) {
    __shared__ int s[512];
    int tid = threadIdx.x;
    int v = (tid < nb) ? bsum[tid] : 0;
    s[tid] = v;
    __syncthreads();
    for (int o = 1; o < 512; o <<= 1) {
        int t = (tid >= o) ? s[tid - o] : 0;
        __syncthreads();
        s[tid] += t;
        __syncthreads();
    }
    if (tid < nb) bsum[tid] = s[tid] - v;            // exclusive
    if (tid == 511) *rs_tail = s[511];               // total (tail padded with 0)
}

// per-chunk exclusive scan + chunk offset -> row_start
__global__ void scandeg_k(const int* __restrict__ deg, const int* __restrict__ bsum,
                          int* __restrict__ row_start, int N) {
    __shared__ int s[256];
    int i = blockIdx.x * 256 + threadIdx.x;
    int v = (i < N) ? deg[i] : 0;
    s[threadIdx.x] = v;
    __syncthreads();
    for (int o = 1; o < 256; o <<= 1) {
        int t = (threadIdx.x >= o) ? s[threadIdx.x - o] : 0;
        __syncthreads();
        s[threadIdx.x] += t;
        __syncthreads();
    }
    if (i < N) row_start[i] = bsum[blockIdx.x] + s[threadIdx.x] - v;
}

__global__ void scatter_k(const int* __restrict__ row, const int* __restrict__ col,
                          const int* __restrict__ row_start, int* __restrict__ cnt,
                          int* __restrict__ col_s, int* __restrict__ eid_s, int E) {
    int e = blockIdx.x * blockDim.x + threadIdx.x;
    if (e >= E) return;
    int r = row[e];
    int pos = row_start[r] + atomicAdd(&cnt[r], 1);
    col_s[pos] = col[e];
    if (eid_s) eid_s[pos] = e;
}

// ================= feature kernels =================

// one wave per node; 64 lanes x float2 = 128 feats; mean over CSR neighbors; fused relu
__global__ void mean_gather_k(const int* __restrict__ row_start, const int* __restrict__ col_s,
                              const float* __restrict__ emb, float* __restrict__ out,
                              int off, int N) {
    int n = blockIdx.x * (blockDim.x >> 6) + (threadIdx.x >> 6);
    int lane = threadIdx.x & 63;
    if (n >= N) return;
    int s = row_start[n], t = row_start[n + 1];
    float2 acc = {0.0f, 0.0f};
    for (int p = s; p < t; ++p) {
        int c = col_s[p];
        float2 v = reinterpret_cast<const float2*>(&emb[(size_t)c * NODE_F])[lane];
        acc.x += v.x; acc.y += v.y;
    }
    if (t > s) {
        float w = 1.0f / (float)(t - s);
        acc.x *= w; acc.y *= w;
    }
    acc.x = acc.x > 0.0f ? acc.x : 0.0f;
    acc.y = acc.y > 0.0f ? acc.y : 0.0f;
    reinterpret_cast<float2*>(&out[(size_t)n * LDO + off])[lane] = acc;
}

__global__ void rel_proj_k(const float* __restrict__ rel_emb, const float* __restrict__ a_rel,
                           float* __restrict__ proj, int R) {
    int r = blockIdx.x * blockDim.x + threadIdx.x;
    if (r >= R) return;
    float s = 0.0f;
    #pragma unroll 4
    for (int f = 0; f < NODE_F; ++f) s += rel_emb[(size_t)r * NODE_F + f] * a_rel[f];
    proj[r] = s;
}

// sp_row == arange(E) (bijection) -> plain store, no atomics
__global__ void rel_attn_map_k(const float* __restrict__ sp_val, const int* __restrict__ sp_row,
                               const int* __restrict__ sp_col, const float* __restrict__ proj,
                               float* __restrict__ rel_attn, int E) {
    int e = blockIdx.x * blockDim.x + threadIdx.x;
    if (e < E) rel_attn[sp_row[e]] = sp_val[e] * proj[sp_col[e]];
}

// one 64-lane wave per node: a_s[n] = feat(n)·a_self, a_n[n] = feat(n)·a_neigh
__global__ void asn_k(const float* __restrict__ out, int off,
                      const float* __restrict__ a_self, const float* __restrict__ a_neigh,
                      float* __restrict__ a_s, float* __restrict__ a_n, int N) {
    int n = blockIdx.x * (blockDim.x >> 6) + (threadIdx.x >> 6);
    int lane = threadIdx.x & 63;
    if (n >= N) return;
    const float4* fp = reinterpret_cast<const float4*>(&out[(size_t)n * LDO + off]);
    float4 v  = fp[lane];
    float4 s4 = reinterpret_cast<const float4*>(a_self)[lane];
    float4 n4 = reinterpret_cast<const float4*>(a_neigh)[lane];
    float ds = v.x * s4.x + v.y * s4.y + v.z * s4.z + v.w * s4.w;
    float dn = v.x * n4.x + v.y * n4.y + v.z * n4.z + v.w * n4.w;
    #pragma unroll
    for (int o = 32; o > 0; o >>= 1) {
        ds += __shfl_down(ds, o);
        dn += __shfl_down(dn, o);
    }
    if (lane == 0) { a_s[n] = ds; a_n[n] = dn; }
}

// per-row softmax over CSR edges; 1 thread per row, 3 cached passes.
// att_s: normalized att in SORTED order; att_out (original order) written when non-null.
__global__ void softmax_row_k(const int* __restrict__ row_start, const int* __restrict__ col_s,
                              const int* __restrict__ eid_s, const float* __restrict__ rel_attn,
                              const float* __restrict__ a_s, const float* __restrict__ a_n,
                              float* __restrict__ att_s, float* __restrict__ att_out, int N) {
    int n = blockIdx.x * blockDim.x + threadIdx.x;
    if (n >= N) return;
    int s = row_start[n], t = row_start[n + 1];
    if (s == t) return;
    float as = a_s[n];
    float m = -3.4e38f;
    for (int p = s; p < t; ++p) {
        float v = rel_attn[eid_s[p]] + as + a_n[col_s[p]];
        v = v >= 0.0f ? v : 0.2f * v;          // leaky relu
        att_s[p] = v;
        m = v > m ? v : m;
    }
    float sum = 0.0f;
    for (int p = s; p < t; ++p) {
        float ex = __expf(att_s[p] - m);
        att_s[p] = ex;
        sum += ex;
    }
    float inv = 1.0f / sum;
    for (int p = s; p < t; ++p) {
        float a = att_s[p] * inv;
        att_s[p] = a;
        if (att_out) att_out[eid_s[p]] = a;
    }
}

// one wave per row; 64 lanes x float4 = 256 feats; gather att*feat over CSR; fused relu
__global__ void agg_gather_k(const int* __restrict__ row_start, const int* __restrict__ col_s,
                             const float* __restrict__ att_s, float* __restrict__ out,
                             int src, int dst, int N) {
    int n = blockIdx.x * (blockDim.x >> 6) + (threadIdx.x >> 6);
    int lane = threadIdx.x & 63;
    if (n >= N) return;
    int s = row_start[n], t = row_start[n + 1];
    float4 acc = {0.0f, 0.0f, 0.0f, 0.0f};
    for (int p = s; p < t; ++p) {
        int c = col_s[p];
        float a = att_s[p];
        float4 v = reinterpret_cast<const float4*>(&out[(size_t)c * LDO + src])[lane];
        acc.x += a * v.x; acc.y += a * v.y; acc.z += a * v.z; acc.w += a * v.w;
    }
    acc.x = acc.x > 0.0f ? acc.x : 0.0f;
    acc.y = acc.y > 0.0f ? acc.y : 0.0f;
    acc.z = acc.z > 0.0f ? acc.z : 0.0f;
    acc.w = acc.w > 0.0f ? acc.w : 0.0f;
    reinterpret_cast<float4*>(&out[(size_t)n * LDO + dst])[lane] = acc;
}

// ================= launch =================

extern "C" void kernel_launch(void* const* d_in, const int* in_sizes, int n_in,
                              void* d_out, int out_size, void* d_ws, size_t ws_size,
                              hipStream_t stream) {
    const float* ent_emb = (const float*)d_in[0];
    const float* rel_emb = (const float*)d_in[1];
    const float* a_self  = (const float*)d_in[2];
    const float* a_neigh = (const float*)d_in[3];
    const float* a_rel   = (const float*)d_in[4];
    const float* sp_val  = (const float*)d_in[5];
    const int*   adj_row = (const int*)d_in[6];
    const int*   adj_col = (const int*)d_in[7];
    const int*   sp_row  = (const int*)d_in[8];
    const int*   sp_col  = (const int*)d_in[9];
    const int*   rel_row = (const int*)d_in[10];
    const int*   rel_col = (const int*)d_in[11];
    const int*   ent_row = (const int*)d_in[12];
    const int*   ent_col = (const int*)d_in[13];

    const int N  = in_sizes[0] / NODE_F;
    const int R  = in_sizes[1] / NODE_F;
    const int E  = in_sizes[5];
    const int ER = in_sizes[10];
    const int EE = in_sizes[12];

    float* out = (float*)d_out;
    float* att_out = out + (size_t)N * LDO;

    const int TB = 256;
    const int nb = (N + 255) / 256;            // chunks for scans (must be <= 512)

    // ---- workspace layout ----
    char* w = (char*)d_ws;
    int* deg3     = (int*)w;  w += (size_t)3 * N * 4;       // deg/cursor for adj, ent, rel
    int* deg_adj  = deg3;
    int* deg_ent  = deg3 + N;
    int* deg_rel  = deg3 + 2 * N;
    int* rs_adj   = (int*)w;  w += (size_t)(N + 1) * 4;
    int* rs_ent   = (int*)w;  w += (size_t)(N + 1) * 4;
    int* rs_rel   = (int*)w;  w += (size_t)(N + 1) * 4;
    int* bs_adj   = (int*)w;  w += 512 * 4;
    int* bs_ent   = (int*)w;  w += 512 * 4;
    int* bs_rel   = (int*)w;  w += 512 * 4;
    int* col_adj  = (int*)w;  w += (size_t)E * 4;
    int* eid_adj  = (int*)w;  w += (size_t)E * 4;
    int* col_ent  = (int*)w;  w += (size_t)EE * 4;
    int* col_rel  = (int*)w;  w += (size_t)ER * 4;
    float* att_s    = (float*)w;  w += (size_t)E * 4;
    float* rel_attn = (float*)w;  w += (size_t)E * 4;
    float* proj     = (float*)w;  w += (size_t)R * 4;
    float* a_s      = (float*)w;  w += (size_t)N * 4;
    float* a_n      = (float*)w;  w += (size_t)N * 4;

    // ---- build 3 CSRs (counting sort by row) ----
    hipMemsetAsync(deg3, 0, (size_t)3 * N * sizeof(int), stream);
    count_deg_k<<<(E  + TB - 1) / TB, TB, 0, stream>>>(adj_row, deg_adj, E);
    count_deg_k<<<(EE + TB - 1) / TB, TB, 0, stream>>>(ent_row, deg_ent, EE);
    count_deg_k<<<(ER + TB - 1) / TB, TB, 0, stream>>>(rel_row, deg_rel, ER);

    blocksum_k<<<nb, 256, 0, stream>>>(deg_adj, bs_adj, N);
    blocksum_k<<<nb, 256, 0, stream>>>(deg_ent, bs_ent, N);
    blocksum_k<<<nb, 256, 0, stream>>>(deg_rel, bs_rel, N);
    scanbsum_k<<<1, 512, 0, stream>>>(bs_adj, nb, rs_adj + N);
    scanbsum_k<<<1, 512, 0, stream>>>(bs_ent, nb, rs_ent + N);
    scanbsum_k<<<1, 512, 0, stream>>>(bs_rel, nb, rs_rel + N);
    scandeg_k<<<nb, 256, 0, stream>>>(deg_adj, bs_adj, rs_adj, N);
    scandeg_k<<<nb, 256, 0, stream>>>(deg_ent, bs_ent, rs_ent, N);
    scandeg_k<<<nb, 256, 0, stream>>>(deg_rel, bs_rel, rs_rel, N);

    hipMemsetAsync(deg3, 0, (size_t)3 * N * sizeof(int), stream);   // reuse as cursors
    scatter_k<<<(E  + TB - 1) / TB, TB, 0, stream>>>(adj_row, adj_col, rs_adj, deg_adj, col_adj, eid_adj, E);
    scatter_k<<<(EE + TB - 1) / TB, TB, 0, stream>>>(ent_row, ent_col, rs_ent, deg_ent, col_ent, nullptr, EE);
    scatter_k<<<(ER + TB - 1) / TB, TB, 0, stream>>>(rel_row, rel_col, rs_rel, deg_rel, col_rel, nullptr, ER);

    // ---- initial features: relu(mean_ent | mean_rel) written straight into out cols 0..255 ----
    mean_gather_k<<<(N + 3) / 4, 256, 0, stream>>>(rs_ent, col_ent, ent_emb, out, 0, N);
    mean_gather_k<<<(N + 3) / 4, 256, 0, stream>>>(rs_rel, col_rel, rel_emb, out, NODE_F, N);

    // ---- relation attention term (constant across depth) ----
    rel_proj_k<<<(R + TB - 1) / TB, TB, 0, stream>>>(rel_emb, a_rel, proj, R);
    rel_attn_map_k<<<(E + TB - 1) / TB, TB, 0, stream>>>(sp_val, sp_row, sp_col, proj, rel_attn, E);

    // ---- 2 depths ----
    for (int d = 1; d <= 2; ++d) {
        const int src = (d - 1) * ENT_F;
        const int dst = d * ENT_F;
        asn_k<<<(N + 3) / 4, 256, 0, stream>>>(out, src, a_self, a_neigh, a_s, a_n, N);
        softmax_row_k<<<nb, 256, 0, stream>>>(rs_adj, col_adj, eid_adj, rel_attn, a_s, a_n,
                                              att_s, (d == 2) ? att_out : nullptr, N);
        agg_gather_k<<<(N + 3) / 4, 256, 0, stream>>>(rs_adj, col_adj, att_s, out, src, dst, N);
    }
}

// Round 3
// 361.620 us; speedup vs baseline: 3.0764x; 1.1746x over previous
//
#include <hip/hip_runtime.h>

#define NODE_F 128
#define ENT_F  256
#define LDO    768   // out row stride: ENT_F * (DEPTH+1)
#define NEG_INF -3.4e38f

// ================= batched CSR build (blockIdx.y = graph: 0=adj,1=ent,2=rel) =================

__global__ void count3_k(const int* __restrict__ r0, const int* __restrict__ r1,
                         const int* __restrict__ r2, int E0, int E1, int E2,
                         int* __restrict__ deg3, int N) {
    int i = blockIdx.x * blockDim.x + threadIdx.x;
    int y = blockIdx.y;
    const int* rp = (y == 0) ? r0 : (y == 1) ? r1 : r2;
    int Eg = (y == 0) ? E0 : (y == 1) ? E1 : E2;
    if (i < Eg) atomicAdd(&deg3[(size_t)y * N + rp[i]], 1);
}

__global__ void blocksum3_k(const int* __restrict__ deg3, int* __restrict__ bs3, int N) {
    __shared__ int s[256];
    int y = blockIdx.y;
    int i = blockIdx.x * 256 + threadIdx.x;
    s[threadIdx.x] = (i < N) ? deg3[(size_t)y * N + i] : 0;
    __syncthreads();
    for (int o = 128; o > 0; o >>= 1) {
        if (threadIdx.x < o) s[threadIdx.x] += s[threadIdx.x + o];
        __syncthreads();
    }
    if (threadIdx.x == 0) bs3[y * 512 + blockIdx.x] = s[0];
}

// exclusive scan of each graph's 512-entry block sums; tail -> rs3[y*(N+1)+N]
__global__ void scanbsum3_k(int* __restrict__ bs3, int nb, int* __restrict__ rs3, int N) {
    __shared__ int s[512];
    int y = blockIdx.x;
    int tid = threadIdx.x;
    int v = (tid < nb) ? bs3[y * 512 + tid] : 0;
    s[tid] = v;
    __syncthreads();
    for (int o = 1; o < 512; o <<= 1) {
        int t = (tid >= o) ? s[tid - o] : 0;
        __syncthreads();
        s[tid] += t;
        __syncthreads();
    }
    if (tid < nb) bs3[y * 512 + tid] = s[tid] - v;      // exclusive
    if (tid == 511) rs3[(size_t)y * (N + 1) + N] = s[511];
}

// per-chunk exclusive scan + chunk offset -> row_start (rs3) and scatter cursor (cur3)
__global__ void scandeg3_k(const int* __restrict__ deg3, const int* __restrict__ bs3,
                           int* __restrict__ rs3, int* __restrict__ cur3, int N) {
    __shared__ int s[256];
    int y = blockIdx.y;
    int i = blockIdx.x * 256 + threadIdx.x;
    int v = (i < N) ? deg3[(size_t)y * N + i] : 0;
    s[threadIdx.x] = v;
    __syncthreads();
    for (int o = 1; o < 256; o <<= 1) {
        int t = (threadIdx.x >= o) ? s[threadIdx.x - o] : 0;
        __syncthreads();
        s[threadIdx.x] += t;
        __syncthreads();
    }
    if (i < N) {
        int rs = bs3[y * 512 + blockIdx.x] + s[threadIdx.x] - v;
        rs3[(size_t)y * (N + 1) + i] = rs;
        cur3[(size_t)y * N + i] = rs;
    }
}

__global__ void scatter3_k(const int* __restrict__ r0, const int* __restrict__ c0,
                           const int* __restrict__ r1, const int* __restrict__ c1,
                           const int* __restrict__ r2, const int* __restrict__ c2,
                           int E0, int E1, int E2, int* __restrict__ cur3,
                           int* __restrict__ col_adj, int* __restrict__ eid_adj,
                           int* __restrict__ col_ent, int* __restrict__ col_rel, int N) {
    int e = blockIdx.x * blockDim.x + threadIdx.x;
    int y = blockIdx.y;
    const int* rp = (y == 0) ? r0 : (y == 1) ? r1 : r2;
    const int* cp = (y == 0) ? c0 : (y == 1) ? c1 : c2;
    int* colp = (y == 0) ? col_adj : (y == 1) ? col_ent : col_rel;
    int Eg = (y == 0) ? E0 : (y == 1) ? E1 : E2;
    if (e >= Eg) return;
    int r = rp[e];
    int pos = atomicAdd(&cur3[(size_t)y * N + r], 1);
    colp[pos] = cp[e];
    if (y == 0) eid_adj[pos] = e;
}

// ================= small map kernels =================

__global__ void rel_proj_k(const float* __restrict__ rel_emb, const float* __restrict__ a_rel,
                           float* __restrict__ proj, int R) {
    int r = blockIdx.x * blockDim.x + threadIdx.x;
    if (r >= R) return;
    float s = 0.0f;
    #pragma unroll 4
    for (int f = 0; f < NODE_F; ++f) s += rel_emb[(size_t)r * NODE_F + f] * a_rel[f];
    proj[r] = s;
}

// sp_row is a bijection (arange) -> plain store
__global__ void rel_attn_map_k(const float* __restrict__ sp_val, const int* __restrict__ sp_row,
                               const int* __restrict__ sp_col, const float* __restrict__ proj,
                               float* __restrict__ rel_attn, int E) {
    int e = blockIdx.x * blockDim.x + threadIdx.x;
    if (e < E) rel_attn[sp_row[e]] = sp_val[e] * proj[sp_col[e]];
}

// ================= fused feature kernels =================

// one wave per node: ent-mean (cols 0..127) + rel-mean (cols 128..255), relu,
// write to out, and compute a_s/a_n dots from in-register features.
__global__ void meanagg_fused_k(const int* __restrict__ rs_ent, const int* __restrict__ col_ent,
                                const int* __restrict__ rs_rel, const int* __restrict__ col_rel,
                                const float* __restrict__ ent_emb, const float* __restrict__ rel_emb,
                                const float* __restrict__ a_self, const float* __restrict__ a_neigh,
                                float* __restrict__ out, float* __restrict__ a_s_out,
                                float* __restrict__ a_n_out, int N) {
    int n = blockIdx.x * (blockDim.x >> 6) + (threadIdx.x >> 6);
    int lane = threadIdx.x & 63;
    if (n >= N) return;

    int s = rs_ent[n], t = rs_ent[n + 1];
    float2 ea = {0.0f, 0.0f};
    for (int p = s; p < t; ++p) {
        float2 v = reinterpret_cast<const float2*>(&ent_emb[(size_t)col_ent[p] * NODE_F])[lane];
        ea.x += v.x; ea.y += v.y;
    }
    if (t > s) { float w = 1.0f / (float)(t - s); ea.x *= w; ea.y *= w; }

    s = rs_rel[n]; t = rs_rel[n + 1];
    float2 ra = {0.0f, 0.0f};
    for (int p = s; p < t; ++p) {
        float2 v = reinterpret_cast<const float2*>(&rel_emb[(size_t)col_rel[p] * NODE_F])[lane];
        ra.x += v.x; ra.y += v.y;
    }
    if (t > s) { float w = 1.0f / (float)(t - s); ra.x *= w; ra.y *= w; }

    ea.x = ea.x > 0.0f ? ea.x : 0.0f;  ea.y = ea.y > 0.0f ? ea.y : 0.0f;
    ra.x = ra.x > 0.0f ? ra.x : 0.0f;  ra.y = ra.y > 0.0f ? ra.y : 0.0f;

    reinterpret_cast<float2*>(&out[(size_t)n * LDO])[lane] = ea;
    reinterpret_cast<float2*>(&out[(size_t)n * LDO + NODE_F])[lane] = ra;

    // a_s / a_n from in-register features; lane covers feats [2l,2l+1] and [128+2l,128+2l+1]
    float2 se = reinterpret_cast<const float2*>(a_self)[lane];
    float2 sr = reinterpret_cast<const float2*>(a_self)[64 + lane];
    float2 ne = reinterpret_cast<const float2*>(a_neigh)[lane];
    float2 nr = reinterpret_cast<const float2*>(a_neigh)[64 + lane];
    float ds = ea.x * se.x + ea.y * se.y + ra.x * sr.x + ra.y * sr.y;
    float dn = ea.x * ne.x + ea.y * ne.y + ra.x * nr.x + ra.y * nr.y;
    #pragma unroll
    for (int o = 32; o > 0; o >>= 1) {
        ds += __shfl_xor(ds, o);
        dn += __shfl_xor(dn, o);
    }
    if (lane == 0) { a_s_out[n] = ds; a_n_out[n] = dn; }
}

// one wave per node: fused softmax (lane-per-edge) + weighted feature gather + relu
// + optional next-depth a_s/a_n + optional att scatter (original edge order).
__global__ void attn_agg_fused_k(const int* __restrict__ rs, const int* __restrict__ col_s,
                                 const int* __restrict__ eid_s, const float* __restrict__ rel_attn,
                                 const float* __restrict__ a_s_in, const float* __restrict__ a_n_in,
                                 const float* __restrict__ a_self, const float* __restrict__ a_neigh,
                                 float* __restrict__ a_s_out, float* __restrict__ a_n_out,
                                 float* __restrict__ out, int src, int dst,
                                 float* __restrict__ att_out, int N) {
    int n = blockIdx.x * (blockDim.x >> 6) + (threadIdx.x >> 6);
    int lane = threadIdx.x & 63;
    if (n >= N) return;
    int s = rs[n], t = rs[n + 1];
    int deg = t - s;
    float4 acc = {0.0f, 0.0f, 0.0f, 0.0f};

    if (deg > 0) {
        float as_row = a_s_in[n];
        if (deg <= 64) {
            float myv = NEG_INF;
            int mycol = 0, myeid = 0;
            if (lane < deg) {
                int p = s + lane;
                mycol = col_s[p];
                myeid = eid_s[p];
                float v = rel_attn[myeid] + as_row + a_n_in[mycol];
                myv = v >= 0.0f ? v : 0.2f * v;
            }
            float m = myv;
            #pragma unroll
            for (int o = 32; o > 0; o >>= 1) {
                float x = __shfl_xor(m, o);
                m = x > m ? x : m;
            }
            float ex = (lane < deg) ? __expf(myv - m) : 0.0f;
            float ssum = ex;
            #pragma unroll
            for (int o = 32; o > 0; o >>= 1) ssum += __shfl_xor(ssum, o);
            float myatt = ex / ssum;
            if (att_out && lane < deg) att_out[myeid] = myatt;
            for (int p = 0; p < deg; ++p) {
                float a = __shfl(myatt, p);
                int c = __shfl(mycol, p);
                float4 v = reinterpret_cast<const float4*>(&out[(size_t)c * LDO + src])[lane];
                acc.x += a * v.x; acc.y += a * v.y; acc.z += a * v.z; acc.w += a * v.w;
            }
        } else {  // rare fallback: deg > 64
            float m = NEG_INF;
            for (int p = s + lane; p < t; p += 64) {
                float v = rel_attn[eid_s[p]] + as_row + a_n_in[col_s[p]];
                v = v >= 0.0f ? v : 0.2f * v;
                m = v > m ? v : m;
            }
            #pragma unroll
            for (int o = 32; o > 0; o >>= 1) {
                float x = __shfl_xor(m, o);
                m = x > m ? x : m;
            }
            float ssum = 0.0f;
            for (int p = s + lane; p < t; p += 64) {
                float v = rel_attn[eid_s[p]] + as_row + a_n_in[col_s[p]];
                v = v >= 0.0f ? v : 0.2f * v;
                ssum += __expf(v - m);
            }
            #pragma unroll
            for (int o = 32; o > 0; o >>= 1) ssum += __shfl_xor(ssum, o);
            float inv = 1.0f / ssum;
            for (int p = s; p < t; ++p) {
                int c = col_s[p], e = eid_s[p];
                float v = rel_attn[e] + as_row + a_n_in[c];
                v = v >= 0.0f ? v : 0.2f * v;
                float a = __expf(v - m) * inv;
                if (att_out && lane == 0) att_out[e] = a;
                float4 fv = reinterpret_cast<const float4*>(&out[(size_t)c * LDO + src])[lane];
                acc.x += a * fv.x; acc.y += a * fv.y; acc.z += a * fv.z; acc.w += a * fv.w;
            }
        }
    }

    acc.x = acc.x > 0.0f ? acc.x : 0.0f;
    acc.y = acc.y > 0.0f ? acc.y : 0.0f;
    acc.z = acc.z > 0.0f ? acc.z : 0.0f;
    acc.w = acc.w > 0.0f ? acc.w : 0.0f;
    reinterpret_cast<float4*>(&out[(size_t)n * LDO + dst])[lane] = acc;

    if (a_s_out) {  // next-depth dots from in-register features; lane covers feats [4l..4l+3]
        float4 s4 = reinterpret_cast<const float4*>(a_self)[lane];
        float4 n4 = reinterpret_cast<const float4*>(a_neigh)[lane];
        float ds = acc.x * s4.x + acc.y * s4.y + acc.z * s4.z + acc.w * s4.w;
        float dn = acc.x * n4.x + acc.y * n4.y + acc.z * n4.z + acc.w * n4.w;
        #pragma unroll
        for (int o = 32; o > 0; o >>= 1) {
            ds += __shfl_xor(ds, o);
            dn += __shfl_xor(dn, o);
        }
        if (lane == 0) { a_s_out[n] = ds; a_n_out[n] = dn; }
    }
}

// ================= launch =================

extern "C" void kernel_launch(void* const* d_in, const int* in_sizes, int n_in,
                              void* d_out, int out_size, void* d_ws, size_t ws_size,
                              hipStream_t stream) {
    const float* ent_emb = (const float*)d_in[0];
    const float* rel_emb = (const float*)d_in[1];
    const float* a_self  = (const float*)d_in[2];
    const float* a_neigh = (const float*)d_in[3];
    const float* a_rel   = (const float*)d_in[4];
    const float* sp_val  = (const float*)d_in[5];
    const int*   adj_row = (const int*)d_in[6];
    const int*   adj_col = (const int*)d_in[7];
    const int*   sp_row  = (const int*)d_in[8];
    const int*   sp_col  = (const int*)d_in[9];
    const int*   rel_row = (const int*)d_in[10];
    const int*   rel_col = (const int*)d_in[11];
    const int*   ent_row = (const int*)d_in[12];
    const int*   ent_col = (const int*)d_in[13];

    const int N  = in_sizes[0] / NODE_F;
    const int R  = in_sizes[1] / NODE_F;
    const int E  = in_sizes[5];
    const int ER = in_sizes[10];
    const int EE = in_sizes[12];

    float* out = (float*)d_out;
    float* att_out = out + (size_t)N * LDO;

    const int TB = 256;
    const int nb = (N + 255) / 256;        // <= 512
    int maxE = E > EE ? E : EE; if (ER > maxE) maxE = ER;

    // ---- workspace ----
    char* w = (char*)d_ws;
    int* deg3    = (int*)w;  w += (size_t)3 * N * 4;
    int* cur3    = (int*)w;  w += (size_t)3 * N * 4;
    int* rs3     = (int*)w;  w += (size_t)3 * (N + 1) * 4;
    int* bs3     = (int*)w;  w += (size_t)3 * 512 * 4;
    int* col_adj = (int*)w;  w += (size_t)E * 4;
    int* eid_adj = (int*)w;  w += (size_t)E * 4;
    int* col_ent = (int*)w;  w += (size_t)EE * 4;
    int* col_rel = (int*)w;  w += (size_t)ER * 4;
    float* rel_attn = (float*)w;  w += (size_t)E * 4;
    float* proj     = (float*)w;  w += (size_t)R * 4;
    float* a_s0     = (float*)w;  w += (size_t)N * 4;
    float* a_n0     = (float*)w;  w += (size_t)N * 4;
    float* a_s1     = (float*)w;  w += (size_t)N * 4;
    float* a_n1     = (float*)w;  w += (size_t)N * 4;

    int* rs_adj = rs3;
    int* rs_ent = rs3 + (N + 1);
    int* rs_rel = rs3 + 2 * (N + 1);

    // ---- batched CSR build ----
    hipMemsetAsync(deg3, 0, (size_t)3 * N * sizeof(int), stream);
    {
        dim3 g((maxE + TB - 1) / TB, 3);
        count3_k<<<g, TB, 0, stream>>>(adj_row, ent_row, rel_row, E, EE, ER, deg3, N);
    }
    {
        dim3 g(nb, 3);
        blocksum3_k<<<g, 256, 0, stream>>>(deg3, bs3, N);
        scanbsum3_k<<<3, 512, 0, stream>>>(bs3, nb, rs3, N);
        scandeg3_k<<<g, 256, 0, stream>>>(deg3, bs3, rs3, cur3, N);
    }
    {
        dim3 g((maxE + TB - 1) / TB, 3);
        scatter3_k<<<g, TB, 0, stream>>>(adj_row, adj_col, ent_row, ent_col, rel_row, rel_col,
                                         E, EE, ER, cur3, col_adj, eid_adj, col_ent, col_rel, N);
    }

    // ---- relation attention term ----
    rel_proj_k<<<(R + TB - 1) / TB, TB, 0, stream>>>(rel_emb, a_rel, proj, R);
    rel_attn_map_k<<<(E + TB - 1) / TB, TB, 0, stream>>>(sp_val, sp_row, sp_col, proj, rel_attn, E);

    // ---- initial features + depth-1 a_s/a_n ----
    meanagg_fused_k<<<(N + 3) / 4, 256, 0, stream>>>(rs_ent, col_ent, rs_rel, col_rel,
                                                     ent_emb, rel_emb, a_self, a_neigh,
                                                     out, a_s0, a_n0, N);

    // ---- depth 1: softmax+agg+relu, also compute depth-2 a_s/a_n ----
    attn_agg_fused_k<<<(N + 3) / 4, 256, 0, stream>>>(rs_adj, col_adj, eid_adj, rel_attn,
                                                      a_s0, a_n0, a_self, a_neigh, a_s1, a_n1,
                                                      out, 0, ENT_F, nullptr, N);

    // ---- depth 2: softmax+agg+relu, emit att ----
    attn_agg_fused_k<<<(N + 3) / 4, 256, 0, stream>>>(rs_adj, col_adj, eid_adj, rel_attn,
                                                      a_s1, a_n1, nullptr, nullptr, nullptr, nullptr,
                                                      out, ENT_F, 2 * ENT_F, att_out, N);
}